// Round 8
// baseline (214.126 us; speedup 1.0000x reference)
//
#include <hip/hip_runtime.h>
#include <math.h>

// LeNet-ish forward, fp32, B=8192.
// conv1+pool = stride-2 6x6 conv (w6 = W1 (*) ones(2,2), /4 at use).
// conv1 -> S1 (2x2 window-sum of sigmoid output) in LDS -> conv2 (S-trick)
// in the same kernel. h2 contiguous [B][320] (r6's interleaved layout caused
// a 26x write-amplification RFO storm - never scalar-scatter to global).
// FC: transposed LDS activations (stride 36: f4-aligned + conflict-free),
// 8-deep rotating weight prefetch for ILP.
//
// ws: [w6 4KB][w2q 32KB][L2p 64KB][h2: B*320 f32]

__device__ __forceinline__ float sigf(float v) {
    return 1.0f / (1.0f + __expf(-v));
}

// --- K0: prep. w6[ky][c][8] from W1; w2q repack; L2 pad 84->88. ---
__global__ void k_prep(const float* __restrict__ W1, const float* __restrict__ W2,
                       const float* __restrict__ L2, float* __restrict__ w6,
                       float* __restrict__ w2q, float* __restrict__ L2p) {
    int i = blockIdx.x * 256 + threadIdx.x;
    if (i < 5000) {
        int kx = i % 5, t = i / 5;
        int ky = t % 5, t2 = t / 5;
        int ic = t2 % 10, c = t2 / 10;
        w2q[((ic * 5 + ky) * 20 + c) * 5 + kx] = W2[i];
    }
    int j = i - 5000;
    if (j >= 0 && j < 10080) L2p[(j / 84) * 88 + (j % 84)] = L2[j];
    int k = i - 15080;
    if (k >= 0 && k < 480) {
        int kx = k % 8, t = k / 8;
        int c = t % 10, ky = t / 10;
        float v = 0.f;
        if (kx < 6) {
            for (int dy = 0; dy < 2; ++dy)
                for (int dx = 0; dx < 2; ++dx) {
                    int sy = ky - dy, sx = kx - dx;
                    if (sy >= 0 && sy < 5 && sx >= 0 && sx < 5)
                        v += W1[c * 25 + sy * 5 + sx];
                }
        }
        w6[k] = v;
    }
}

// --- K1: fused convs. 512 threads, 8 img/block, 1024 blocks. ---
// LDS: S1t 43.1K + XW(union: XR 25.1K | w2s 20K) + wq1 1.9K ~= 70.3K -> 2 blk/CU.
// Phase B: wave=image, lane=(cc<5 ch-pair, py<12); reads x rows from LDS
//          (12 distinct rows/wave -> <=2-way bank alias = free).
// Phase C: 160 thr = (im-pair4, cg5, py4, xh2), acc[4oc][2im][2px]:
//          W amortized over 2 images -> ~9 b128 / 160 FMA (halves LDS instrs).
#define S1STR 1348  // 1348%32==4 -> image slabs bank-staggered

__global__ __launch_bounds__(512, 4) void k_convs(
    const float* __restrict__ x, const float* __restrict__ w6g,
    const float* __restrict__ b1, const float* __restrict__ w2qg,
    const float* __restrict__ b2, float* __restrict__ h2) {
    __shared__ float S1t[8 * S1STR];   // 43136 B
    __shared__ float XW[6272];         // XR [im8][784] during B; w2s[5000] in C
    __shared__ float wq1[480];         // [ky6][ch10][8]
    __shared__ float bs1[10];
    __shared__ float bs2[20];

    const int tid = threadIdx.x;
    const long img0 = (long)blockIdx.x * 8;

    {   // stage x tile (coalesced f4) + conv1 weights
        const float4* xg = (const float4*)(x + img0 * 784);
        float4* xl = (float4*)XW;
        for (int i = tid; i < 1568; i += 512) xl[i] = xg[i];
    }
    if (tid < 480) wq1[tid] = w6g[tid];
    else if (tid < 490) bs1[tid - 480] = b1[tid - 480];
    else if (tid < 510) bs2[tid - 490] = b2[tid - 490];
    __syncthreads();

    // ---- phase B: conv1(6x6 s2) + sigmoid + 2x2 window-sum -> S1t ----
    {
        const int im = tid >> 6, l = tid & 63;
        if (l < 60) {
            const int cc = l / 12, py = l % 12, ch0 = cc * 2;
            float acc0[12], acc1[12];
#pragma unroll
            for (int p = 0; p < 12; ++p) { acc0[p] = 0.f; acc1[p] = 0.f; }

            const float* xim = XW + im * 784;
#pragma unroll
            for (int ky = 0; ky < 6; ++ky) {
                const int r = 2 * py + ky;
                union { float4 v[7]; float f[28]; } R;
                const float4* rp = (const float4*)(xim + r * 28);
#pragma unroll
                for (int q = 0; q < 7; ++q) R.v[q] = rp[q];
                union { float4 v[2]; float f[8]; } W0, W1;
                const float* wb = &wq1[(ky * 10 + ch0) * 8];
                W0.v[0] = *(const float4*)(wb);
                W0.v[1] = *(const float4*)(wb + 4);
                W1.v[0] = *(const float4*)(wb + 8);
                W1.v[1] = *(const float4*)(wb + 12);
#pragma unroll
                for (int kx = 0; kx < 6; ++kx) {
                    const float w0 = W0.f[kx], w1 = W1.f[kx];
#pragma unroll
                    for (int px = 0; px < 12; ++px) {
                        const float xv = R.f[2 * px + kx];
                        acc0[px] += xv * w0;
                        acc1[px] += xv * w1;
                    }
                }
            }

#define FINISH_CH(ACC, CH)                                                   \
            {                                                                \
                float h[12];                                                 \
                _Pragma("unroll")                                            \
                for (int px = 0; px < 12; ++px)                              \
                    h[px] = sigf(ACC[px] * 0.25f + bs1[CH]);                 \
                float hh[11];                                                \
                _Pragma("unroll")                                            \
                for (int t = 0; t < 11; ++t) hh[t] = h[t] + h[t + 1];        \
                float o[12];                                                 \
                _Pragma("unroll")                                            \
                for (int t = 0; t < 11; ++t)                                 \
                    o[t] = hh[t] + __shfl_down(hh[t], 1, 64);                \
                o[11] = 0.f;                                                 \
                if (py < 11) {                                               \
                    float* sp = S1t + im * S1STR + (CH) * 132 + py * 12;     \
                    ((float4*)sp)[0] = make_float4(o[0], o[1], o[2], o[3]);  \
                    ((float4*)sp)[1] = make_float4(o[4], o[5], o[6], o[7]);  \
                    ((float4*)sp)[2] = make_float4(o[8], o[9], o[10], o[11]);\
                }                                                            \
            }
            FINISH_CH(acc0, ch0)
            FINISH_CH(acc1, ch0 + 1)
#undef FINISH_CH
        }
    }
    __syncthreads();

    // stage conv2 weights into the (now dead) x-tile region
    for (int i = tid; i < 5000; i += 512) XW[i] = w2qg[i];
    __syncthreads();

    // ---- phase C: conv2 + pool + sigmoid -> h2 contiguous ----
    if (tid < 160) {
        const int imp = tid / 40, r = tid % 40;
        const int cg = r / 8, py = (r >> 1) & 3, xh = r & 1;
        const int im0 = imp * 2;

        float acc[4][2][2];
#pragma unroll
        for (int a = 0; a < 4; ++a)
#pragma unroll
            for (int b = 0; b < 2; ++b)
#pragma unroll
                for (int c = 0; c < 2; ++c) acc[a][b][c] = 0.f;

        const float* s1a = S1t + (im0 + 0) * S1STR;
        const float* s1b = S1t + (im0 + 1) * S1STR;
        for (int ic = 0; ic < 10; ++ic) {
#pragma unroll
            for (int ky = 0; ky < 5; ++ky) {
                const int ro = ic * 132 + (2 * py + ky) * 12 + xh * 4;
                union { float4 v[2]; float f[8]; } Ra, Rb;
                Ra.v[0] = *(const float4*)(s1a + ro);
                Ra.v[1] = *(const float4*)(s1a + ro + 4);
                Rb.v[0] = *(const float4*)(s1b + ro);
                Rb.v[1] = *(const float4*)(s1b + ro + 4);
                union { float4 v[5]; float f[20]; } W;
                const float4* wp = (const float4*)(XW + (ic * 5 + ky) * 100 + cg * 20);
#pragma unroll
                for (int q = 0; q < 5; ++q) W.v[q] = wp[q];
#pragma unroll
                for (int cc = 0; cc < 4; ++cc)
#pragma unroll
                    for (int kx = 0; kx < 5; ++kx) {
                        const float wv = W.f[cc * 5 + kx];
#pragma unroll
                        for (int p = 0; p < 2; ++p) {
                            acc[cc][0][p] += Ra.f[2 * p + kx] * wv;
                            acc[cc][1][p] += Rb.f[2 * p + kx] * wv;
                        }
                    }
            }
        }

#pragma unroll
        for (int ima = 0; ima < 2; ++ima) {
            float* outp = h2 + (img0 + im0 + ima) * 320 + (cg * 4) * 16 + py * 4 + xh * 2;
#pragma unroll
            for (int cc = 0; cc < 4; ++cc) {
                const float bv = bs2[cg * 4 + cc];
                float2 o;
                o.x = sigf(acc[cc][ima][0] * 0.25f + bv);
                o.y = sigf(acc[cc][ima][1] * 0.25f + bv);
                *(float2*)(outp + cc * 16) = o;
            }
        }
    }
}

// --- K2: FC chain. 32 img/block, grid 256, 256 threads. ---
// Transposed LDS activations, stride 36 (f4-aligned reads + conflict-free
// scatter writes). 8-deep rotating weight prefetch forces outstanding loads.
__global__ __launch_bounds__(256, 2) void k_fc(
    const float* __restrict__ h2, const float* __restrict__ L1,
    const float* __restrict__ Lb1, const float* __restrict__ L2p,
    const float* __restrict__ Lb2, const float* __restrict__ L3,
    const float* __restrict__ Lb3, float* __restrict__ out) {
    __shared__ float h2t[320 * 36];  // 46080 B  [feat][img]
    __shared__ float g1t[120 * 36];  // 17280
    __shared__ float g2t[84 * 36];   // 12096
    __shared__ float L3s[856];       // L3 840 + Lb3 10

    const int tid = threadIdx.x;
    const long img0 = (long)blockIdx.x * 32;

    // stage h2t transposed: f4 read (4 feats, 1 img) -> 4 scalar LDS writes
    // write bank = (16fq + 4q + im) % 32: im distinct per lane -> conflict-free
    for (int i = tid; i < 2560; i += 256) {
        const int fq = i >> 5, im = i & 31;
        float4 v = *(const float4*)(h2 + (img0 + im) * 320 + fq * 4);
        h2t[(fq * 4 + 0) * 36 + im] = v.x;
        h2t[(fq * 4 + 1) * 36 + im] = v.y;
        h2t[(fq * 4 + 2) * 36 + im] = v.z;
        h2t[(fq * 4 + 3) * 36 + im] = v.w;
    }
    for (int i = tid; i < 840; i += 256) L3s[i] = L3[i];
    if (tid < 10) L3s[840 + tid] = Lb3[tid];
    __syncthreads();

    const int og = tid >> 5, jg = tid & 31, i0 = og * 4;

    // ---- FC1: 320 -> 120 ----
    {
        const int jc = jg < 30 ? jg : 29;
        union { float4 v; float f[4]; } bv;
        bv.v = *(const float4*)(Lb1 + jc * 4);
        float acc[4][4];
#pragma unroll
        for (int q = 0; q < 4; ++q)
#pragma unroll
            for (int p = 0; p < 4; ++p) acc[q][p] = bv.f[q];

        const float* wbase = L1 + jc * 4;
        float4 wb[8];
#pragma unroll
        for (int k = 0; k < 8; ++k) wb[k] = *(const float4*)(wbase + k * 120);
        for (int ii = 0; ii < 320; ii += 8) {
#pragma unroll
            for (int k = 0; k < 8; ++k) {
                union { float4 v; float f[4]; } w;
                w.v = wb[k];
                const int ip = (ii + k + 8 < 320) ? ii + k + 8 : 0;
                wb[k] = *(const float4*)(wbase + ip * 120);
                union { float4 v; float f[4]; } h;
                h.v = *(const float4*)&h2t[(ii + k) * 36 + i0];
#pragma unroll
                for (int q = 0; q < 4; ++q) {
                    acc[q][0] += w.f[q] * h.f[0];
                    acc[q][1] += w.f[q] * h.f[1];
                    acc[q][2] += w.f[q] * h.f[2];
                    acc[q][3] += w.f[q] * h.f[3];
                }
            }
        }
        if (jg < 30) {
#pragma unroll
            for (int q = 0; q < 4; ++q) {
                float4 o;
                o.x = sigf(acc[q][0]); o.y = sigf(acc[q][1]);
                o.z = sigf(acc[q][2]); o.w = sigf(acc[q][3]);
                *(float4*)&g1t[(jg * 4 + q) * 36 + i0] = o;
            }
        }
    }
    __syncthreads();

    // ---- FC2: 120 -> 84 ----
    if (jg < 21) {
        union { float4 v; float f[4]; } bv;
        bv.v = *(const float4*)(Lb2 + jg * 4);
        float acc[4][4];
#pragma unroll
        for (int q = 0; q < 4; ++q)
#pragma unroll
            for (int p = 0; p < 4; ++p) acc[q][p] = bv.f[q];

        const float* wbase = L2p + jg * 4;
        float4 wb[8];
#pragma unroll
        for (int k = 0; k < 8; ++k) wb[k] = *(const float4*)(wbase + k * 88);
        for (int ii = 0; ii < 120; ii += 8) {
#pragma unroll
            for (int k = 0; k < 8; ++k) {
                union { float4 v; float f[4]; } w;
                w.v = wb[k];
                const int ip = (ii + k + 8 < 120) ? ii + k + 8 : 0;
                wb[k] = *(const float4*)(wbase + ip * 88);
                union { float4 v; float f[4]; } h;
                h.v = *(const float4*)&g1t[(ii + k) * 36 + i0];
#pragma unroll
                for (int q = 0; q < 4; ++q) {
                    acc[q][0] += w.f[q] * h.f[0];
                    acc[q][1] += w.f[q] * h.f[1];
                    acc[q][2] += w.f[q] * h.f[2];
                    acc[q][3] += w.f[q] * h.f[3];
                }
            }
        }
#pragma unroll
        for (int q = 0; q < 4; ++q) {
            float4 o;
            o.x = sigf(acc[q][0]); o.y = sigf(acc[q][1]);
            o.z = sigf(acc[q][2]); o.w = sigf(acc[q][3]);
            *(float4*)&g2t[(jg * 4 + q) * 36 + i0] = o;
        }
    }
    __syncthreads();

    // ---- FC3: 84 -> 10 ----
    for (int idx = tid; idx < 320; idx += 256) {
        const int im = idx / 10, j = idx % 10;
        float a = L3s[840 + j];
#pragma unroll 4
        for (int i = 0; i < 84; ++i)
            a += g2t[i * 36 + im] * L3s[i * 10 + j];
        out[(img0 + im) * 10 + j] = a;
    }
}

extern "C" void kernel_launch(void* const* d_in, const int* in_sizes, int n_in,
                              void* d_out, int out_size, void* d_ws, size_t ws_size,
                              hipStream_t stream) {
    const float* x   = (const float*)d_in[0];
    const float* W1  = (const float*)d_in[1];
    const float* b1  = (const float*)d_in[2];
    const float* W2  = (const float*)d_in[3];
    const float* b2  = (const float*)d_in[4];
    const float* L1  = (const float*)d_in[5];
    const float* Lb1 = (const float*)d_in[6];
    const float* L2  = (const float*)d_in[7];
    const float* Lb2 = (const float*)d_in[8];
    const float* L3  = (const float*)d_in[9];
    const float* Lb3 = (const float*)d_in[10];
    float* out = (float*)d_out;

    const int B = in_sizes[0] / 784;  // 8192

    char* ws = (char*)d_ws;
    float* w6  = (float*)ws;                        // 1.9KB (pad 4KB)
    float* w2q = (float*)(ws + 4096);               // 20KB (pad 32KB)
    float* L2p = (float*)(ws + 4096 + 32768);       // 42.2KB (pad 64KB)
    float* h2  = (float*)(ws + 4096 + 32768 + 65536);

    hipLaunchKernelGGL(k_prep, dim3(61), dim3(256), 0, stream, W1, W2, L2, w6, w2q, L2p);
    hipLaunchKernelGGL(k_convs, dim3(B / 8), dim3(512), 0, stream, x, w6, b1, w2q, b2, h2);
    hipLaunchKernelGGL(k_fc, dim3(B / 32), dim3(256), 0, stream,
                       h2, L1, Lb1, L2p, Lb2, L3, Lb3, out);
}

// Round 9
// 168.195 us; speedup vs baseline: 1.2731x; 1.2731x over previous
//
#include <hip/hip_runtime.h>
#include <math.h>

// LeNet-ish forward, fp32, B=8192.
// conv1+pool = stride-2 6x6 conv (w6 = W1 (*) ones(2,2), /4 at use).
// conv1 -> S1 (2x2 window-sum of sigmoid output) in LDS -> conv2 (S-trick)
// in the same kernel. h2 contiguous [B][320].
// r8 FIX: __launch_bounds__(512,4) capped VGPR at 64 -> phase-B accumulators
// spilled to scratch (HBM): 275MB writes/145MB reads observed in r6+r7.
// Min-waves arg removed; LDS already caps residency at 2 blocks/CU.
//
// ws: [w6 4KB][w2q 32KB][L2p 64KB][h2: B*320 f32]

__device__ __forceinline__ float sigf(float v) {
    return 1.0f / (1.0f + __expf(-v));
}

// --- K0: prep. w6[ky][c][8] from W1; w2q repack; L2 pad 84->88. ---
__global__ void k_prep(const float* __restrict__ W1, const float* __restrict__ W2,
                       const float* __restrict__ L2, float* __restrict__ w6,
                       float* __restrict__ w2q, float* __restrict__ L2p) {
    int i = blockIdx.x * 256 + threadIdx.x;
    if (i < 5000) {
        int kx = i % 5, t = i / 5;
        int ky = t % 5, t2 = t / 5;
        int ic = t2 % 10, c = t2 / 10;
        w2q[((ic * 5 + ky) * 20 + c) * 5 + kx] = W2[i];
    }
    int j = i - 5000;
    if (j >= 0 && j < 10080) L2p[(j / 84) * 88 + (j % 84)] = L2[j];
    int k = i - 15080;
    if (k >= 0 && k < 480) {
        int kx = k % 8, t = k / 8;
        int c = t % 10, ky = t / 10;
        float v = 0.f;
        if (kx < 6) {
            for (int dy = 0; dy < 2; ++dy)
                for (int dx = 0; dx < 2; ++dx) {
                    int sy = ky - dy, sx = kx - dx;
                    if (sy >= 0 && sy < 5 && sx >= 0 && sx < 5)
                        v += W1[c * 25 + sy * 5 + sx];
                }
        }
        w6[k] = v;
    }
}

// --- K1: fused convs. 512 threads, 8 img/block, 1024 blocks. ---
// LDS: S1t 43.1K + XW(union: XR 25.1K | w2s 20K) + wq1 1.9K ~= 70.3K -> 2 blk/CU.
// Phase B: wave=image, lane=(cc<5 ch-pair, py<12).
// Phase C: 160 thr = (im-pair4, cg5, py4, xh2), acc[4oc][2im][2px].
#define S1STR 1348  // 1348%32==4 -> image slabs bank-staggered

__global__ __launch_bounds__(512) void k_convs(
    const float* __restrict__ x, const float* __restrict__ w6g,
    const float* __restrict__ b1, const float* __restrict__ w2qg,
    const float* __restrict__ b2, float* __restrict__ h2) {
    __shared__ float S1t[8 * S1STR];   // 43136 B
    __shared__ float XW[6272];         // XR [im8][784] during B; w2s[5000] in C
    __shared__ float wq1[480];         // [ky6][ch10][8]
    __shared__ float bs1[10];
    __shared__ float bs2[20];

    const int tid = threadIdx.x;
    const long img0 = (long)blockIdx.x * 8;

    {   // stage x tile (coalesced f4) + conv1 weights
        const float4* xg = (const float4*)(x + img0 * 784);
        float4* xl = (float4*)XW;
        for (int i = tid; i < 1568; i += 512) xl[i] = xg[i];
    }
    if (tid < 480) wq1[tid] = w6g[tid];
    else if (tid < 490) bs1[tid - 480] = b1[tid - 480];
    else if (tid < 510) bs2[tid - 490] = b2[tid - 490];
    __syncthreads();

    // ---- phase B: conv1(6x6 s2) + sigmoid + 2x2 window-sum -> S1t ----
    {
        const int im = tid >> 6, l = tid & 63;
        if (l < 60) {
            const int cc = l / 12, py = l % 12, ch0 = cc * 2;
            float acc0[12], acc1[12];
#pragma unroll
            for (int p = 0; p < 12; ++p) { acc0[p] = 0.f; acc1[p] = 0.f; }

            const float* xim = XW + im * 784;
#pragma unroll
            for (int ky = 0; ky < 6; ++ky) {
                const int r = 2 * py + ky;
                union { float4 v[7]; float f[28]; } R;
                const float4* rp = (const float4*)(xim + r * 28);
#pragma unroll
                for (int q = 0; q < 7; ++q) R.v[q] = rp[q];
                union { float4 v[2]; float f[8]; } W0, W1;
                const float* wb = &wq1[(ky * 10 + ch0) * 8];
                W0.v[0] = *(const float4*)(wb);
                W0.v[1] = *(const float4*)(wb + 4);
                W1.v[0] = *(const float4*)(wb + 8);
                W1.v[1] = *(const float4*)(wb + 12);
#pragma unroll
                for (int kx = 0; kx < 6; ++kx) {
                    const float w0 = W0.f[kx], w1 = W1.f[kx];
#pragma unroll
                    for (int px = 0; px < 12; ++px) {
                        const float xv = R.f[2 * px + kx];
                        acc0[px] += xv * w0;
                        acc1[px] += xv * w1;
                    }
                }
            }

#define FINISH_CH(ACC, CH)                                                   \
            {                                                                \
                float h[12];                                                 \
                _Pragma("unroll")                                            \
                for (int px = 0; px < 12; ++px)                              \
                    h[px] = sigf(ACC[px] * 0.25f + bs1[CH]);                 \
                float hh[11];                                                \
                _Pragma("unroll")                                            \
                for (int t = 0; t < 11; ++t) hh[t] = h[t] + h[t + 1];        \
                float o[12];                                                 \
                _Pragma("unroll")                                            \
                for (int t = 0; t < 11; ++t)                                 \
                    o[t] = hh[t] + __shfl_down(hh[t], 1, 64);                \
                o[11] = 0.f;                                                 \
                if (py < 11) {                                               \
                    float* sp = S1t + im * S1STR + (CH) * 132 + py * 12;     \
                    ((float4*)sp)[0] = make_float4(o[0], o[1], o[2], o[3]);  \
                    ((float4*)sp)[1] = make_float4(o[4], o[5], o[6], o[7]);  \
                    ((float4*)sp)[2] = make_float4(o[8], o[9], o[10], o[11]);\
                }                                                            \
            }
            FINISH_CH(acc0, ch0)
            FINISH_CH(acc1, ch0 + 1)
#undef FINISH_CH
        }
    }
    __syncthreads();

    // stage conv2 weights into the (now dead) x-tile region
    for (int i = tid; i < 5000; i += 512) XW[i] = w2qg[i];
    __syncthreads();

    // ---- phase C: conv2 + pool + sigmoid -> h2 contiguous ----
    if (tid < 160) {
        const int imp = tid / 40, r = tid % 40;
        const int cg = r / 8, py = (r >> 1) & 3, xh = r & 1;
        const int im0 = imp * 2;

        float acc[4][2][2];
#pragma unroll
        for (int a = 0; a < 4; ++a)
#pragma unroll
            for (int b = 0; b < 2; ++b)
#pragma unroll
                for (int c = 0; c < 2; ++c) acc[a][b][c] = 0.f;

        const float* s1a = S1t + (im0 + 0) * S1STR;
        const float* s1b = S1t + (im0 + 1) * S1STR;
        for (int ic = 0; ic < 10; ++ic) {
#pragma unroll
            for (int ky = 0; ky < 5; ++ky) {
                const int ro = ic * 132 + (2 * py + ky) * 12 + xh * 4;
                union { float4 v[2]; float f[8]; } Ra, Rb;
                Ra.v[0] = *(const float4*)(s1a + ro);
                Ra.v[1] = *(const float4*)(s1a + ro + 4);
                Rb.v[0] = *(const float4*)(s1b + ro);
                Rb.v[1] = *(const float4*)(s1b + ro + 4);
                union { float4 v[5]; float f[20]; } W;
                const float4* wp = (const float4*)(XW + (ic * 5 + ky) * 100 + cg * 20);
#pragma unroll
                for (int q = 0; q < 5; ++q) W.v[q] = wp[q];
#pragma unroll
                for (int cc = 0; cc < 4; ++cc)
#pragma unroll
                    for (int kx = 0; kx < 5; ++kx) {
                        const float wv = W.f[cc * 5 + kx];
#pragma unroll
                        for (int p = 0; p < 2; ++p) {
                            acc[cc][0][p] += Ra.f[2 * p + kx] * wv;
                            acc[cc][1][p] += Rb.f[2 * p + kx] * wv;
                        }
                    }
            }
        }

#pragma unroll
        for (int ima = 0; ima < 2; ++ima) {
            float* outp = h2 + (img0 + im0 + ima) * 320 + (cg * 4) * 16 + py * 4 + xh * 2;
#pragma unroll
            for (int cc = 0; cc < 4; ++cc) {
                const float bv = bs2[cg * 4 + cc];
                float2 o;
                o.x = sigf(acc[cc][ima][0] * 0.25f + bv);
                o.y = sigf(acc[cc][ima][1] * 0.25f + bv);
                *(float2*)(outp + cc * 16) = o;
            }
        }
    }
}

// --- K2: FC chain. 32 img/block, grid 256, 256 threads. ---
// Transposed LDS activations, stride 36 (f4-aligned reads + conflict-free
// scatter writes). 8-deep rotating weight prefetch forces outstanding loads.
__global__ __launch_bounds__(256) void k_fc(
    const float* __restrict__ h2, const float* __restrict__ L1,
    const float* __restrict__ Lb1, const float* __restrict__ L2p,
    const float* __restrict__ Lb2, const float* __restrict__ L3,
    const float* __restrict__ Lb3, float* __restrict__ out) {
    __shared__ float h2t[320 * 36];  // 46080 B  [feat][img]
    __shared__ float g1t[120 * 36];  // 17280
    __shared__ float g2t[84 * 36];   // 12096
    __shared__ float L3s[856];       // L3 840 + Lb3 10

    const int tid = threadIdx.x;
    const long img0 = (long)blockIdx.x * 32;

    // stage h2t transposed: f4 read (4 feats, 1 img) -> 4 scalar LDS writes
    for (int i = tid; i < 2560; i += 256) {
        const int fq = i >> 5, im = i & 31;
        float4 v = *(const float4*)(h2 + (img0 + im) * 320 + fq * 4);
        h2t[(fq * 4 + 0) * 36 + im] = v.x;
        h2t[(fq * 4 + 1) * 36 + im] = v.y;
        h2t[(fq * 4 + 2) * 36 + im] = v.z;
        h2t[(fq * 4 + 3) * 36 + im] = v.w;
    }
    for (int i = tid; i < 840; i += 256) L3s[i] = L3[i];
    if (tid < 10) L3s[840 + tid] = Lb3[tid];
    __syncthreads();

    const int og = tid >> 5, jg = tid & 31, i0 = og * 4;

    // ---- FC1: 320 -> 120 ----
    {
        const int jc = jg < 30 ? jg : 29;
        union { float4 v; float f[4]; } bv;
        bv.v = *(const float4*)(Lb1 + jc * 4);
        float acc[4][4];
#pragma unroll
        for (int q = 0; q < 4; ++q)
#pragma unroll
            for (int p = 0; p < 4; ++p) acc[q][p] = bv.f[q];

        const float* wbase = L1 + jc * 4;
        float4 wb[8];
#pragma unroll
        for (int k = 0; k < 8; ++k) wb[k] = *(const float4*)(wbase + k * 120);
        for (int ii = 0; ii < 320; ii += 8) {
#pragma unroll
            for (int k = 0; k < 8; ++k) {
                union { float4 v; float f[4]; } w;
                w.v = wb[k];
                const int ip = (ii + k + 8 < 320) ? ii + k + 8 : 0;
                wb[k] = *(const float4*)(wbase + ip * 120);
                union { float4 v; float f[4]; } h;
                h.v = *(const float4*)&h2t[(ii + k) * 36 + i0];
#pragma unroll
                for (int q = 0; q < 4; ++q) {
                    acc[q][0] += w.f[q] * h.f[0];
                    acc[q][1] += w.f[q] * h.f[1];
                    acc[q][2] += w.f[q] * h.f[2];
                    acc[q][3] += w.f[q] * h.f[3];
                }
            }
        }
        if (jg < 30) {
#pragma unroll
            for (int q = 0; q < 4; ++q) {
                float4 o;
                o.x = sigf(acc[q][0]); o.y = sigf(acc[q][1]);
                o.z = sigf(acc[q][2]); o.w = sigf(acc[q][3]);
                *(float4*)&g1t[(jg * 4 + q) * 36 + i0] = o;
            }
        }
    }
    __syncthreads();

    // ---- FC2: 120 -> 84 ----
    if (jg < 21) {
        union { float4 v; float f[4]; } bv;
        bv.v = *(const float4*)(Lb2 + jg * 4);
        float acc[4][4];
#pragma unroll
        for (int q = 0; q < 4; ++q)
#pragma unroll
            for (int p = 0; p < 4; ++p) acc[q][p] = bv.f[q];

        const float* wbase = L2p + jg * 4;
        float4 wb[8];
#pragma unroll
        for (int k = 0; k < 8; ++k) wb[k] = *(const float4*)(wbase + k * 88);
        for (int ii = 0; ii < 120; ii += 8) {
#pragma unroll
            for (int k = 0; k < 8; ++k) {
                union { float4 v; float f[4]; } w;
                w.v = wb[k];
                const int ip = (ii + k + 8 < 120) ? ii + k + 8 : 0;
                wb[k] = *(const float4*)(wbase + ip * 88);
                union { float4 v; float f[4]; } h;
                h.v = *(const float4*)&g1t[(ii + k) * 36 + i0];
#pragma unroll
                for (int q = 0; q < 4; ++q) {
                    acc[q][0] += w.f[q] * h.f[0];
                    acc[q][1] += w.f[q] * h.f[1];
                    acc[q][2] += w.f[q] * h.f[2];
                    acc[q][3] += w.f[q] * h.f[3];
                }
            }
        }
#pragma unroll
        for (int q = 0; q < 4; ++q) {
            float4 o;
            o.x = sigf(acc[q][0]); o.y = sigf(acc[q][1]);
            o.z = sigf(acc[q][2]); o.w = sigf(acc[q][3]);
            *(float4*)&g2t[(jg * 4 + q) * 36 + i0] = o;
        }
    }
    __syncthreads();

    // ---- FC3: 84 -> 10 ----
    for (int idx = tid; idx < 320; idx += 256) {
        const int im = idx / 10, j = idx % 10;
        float a = L3s[840 + j];
#pragma unroll 4
        for (int i = 0; i < 84; ++i)
            a += g2t[i * 36 + im] * L3s[i * 10 + j];
        out[(img0 + im) * 10 + j] = a;
    }
}

extern "C" void kernel_launch(void* const* d_in, const int* in_sizes, int n_in,
                              void* d_out, int out_size, void* d_ws, size_t ws_size,
                              hipStream_t stream) {
    const float* x   = (const float*)d_in[0];
    const float* W1  = (const float*)d_in[1];
    const float* b1  = (const float*)d_in[2];
    const float* W2  = (const float*)d_in[3];
    const float* b2  = (const float*)d_in[4];
    const float* L1  = (const float*)d_in[5];
    const float* Lb1 = (const float*)d_in[6];
    const float* L2  = (const float*)d_in[7];
    const float* Lb2 = (const float*)d_in[8];
    const float* L3  = (const float*)d_in[9];
    const float* Lb3 = (const float*)d_in[10];
    float* out = (float*)d_out;

    const int B = in_sizes[0] / 784;  // 8192

    char* ws = (char*)d_ws;
    float* w6  = (float*)ws;                        // 1.9KB (pad 4KB)
    float* w2q = (float*)(ws + 4096);               // 20KB (pad 32KB)
    float* L2p = (float*)(ws + 4096 + 32768);       // 42.2KB (pad 64KB)
    float* h2  = (float*)(ws + 4096 + 32768 + 65536);

    hipLaunchKernelGGL(k_prep, dim3(61), dim3(256), 0, stream, W1, W2, L2, w6, w2q, L2p);
    hipLaunchKernelGGL(k_convs, dim3(B / 8), dim3(512), 0, stream, x, w6, b1, w2q, b2, h2);
    hipLaunchKernelGGL(k_fc, dim3(B / 32), dim3(256), 0, stream,
                       h2, L1, Lb1, L2p, Lb2, L3, Lb3, out);
}